// Round 1
// baseline (660.510 us; speedup 1.0000x reference)
//
#include <hip/hip_runtime.h>
#include <hip/hip_bf16.h>

#define T_DIM 8192
#define H_DIM 2048
#define F_DIM 5632

typedef __attribute__((ext_vector_type(4))) float f32x4;
typedef __attribute__((ext_vector_type(8))) short bf16x8;

static __device__ __forceinline__ void gload16(const void* g, void* l) {
    __builtin_amdgcn_global_load_lds(
        (const __attribute__((address_space(1))) void*)g,
        (__attribute__((address_space(3))) void*)l,
        16, 0, 0);
}

static __device__ __forceinline__ unsigned short f2bf(float f) {
    unsigned int u = __float_as_uint(f);
    u += 0x7fffu + ((u >> 16) & 1u);
    return (unsigned short)(u >> 16);
}

// ---- f32 -> bf16 conversion (optionally expert-sliced) ----
__global__ __launch_bounds__(256)
void cvt_f32_bf16(const float* __restrict__ base, const int* __restrict__ eidx,
                  long per_expert, unsigned short* __restrict__ dst, long n)
{
    const float* src = base;
    if (eidx) src += (long)(*eidx) * per_expert;
    const long stride = (long)gridDim.x * blockDim.x;
    for (long i = (long)blockIdx.x * blockDim.x + threadIdx.x; i * 4 < n; i += stride) {
        const float4 v = *(const float4*)(src + i * 4);
        ushort4 o;
        o.x = f2bf(v.x); o.y = f2bf(v.y); o.z = f2bf(v.z); o.w = f2bf(v.w);
        *(ushort4*)(dst + i * 4) = o;
    }
}

// ---- GEMM1 fused: gate = X*W1^T, up = X*W2^T, H = silu(gate)*up ----
// X [T,H] bf16, W1/W2 [F,H] bf16, Hout [T,F] bf16. 128x128 tile, BK=64.
__global__ __launch_bounds__(256, 2)
void gemm1_swiglu(const unsigned short* __restrict__ X,
                  const unsigned short* __restrict__ W1,
                  const unsigned short* __restrict__ W2,
                  unsigned short* __restrict__ Hout)
{
    __shared__ __align__(16) unsigned short sA [128 * 64];
    __shared__ __align__(16) unsigned short sB1[128 * 64];
    __shared__ __align__(16) unsigned short sB2[128 * 64];

    const int tid  = threadIdx.x;
    const int lane = tid & 63;
    const int wid  = tid >> 6;   // 4 waves
    const int wm   = wid >> 1;   // 2x2 wave grid, each wave 64x64 out
    const int wn   = wid & 1;
    const int bm   = blockIdx.y;
    const int bn   = blockIdx.x;

    // staging geometry: wave w covers rows [w*32, w*32+32), 4 issues of 1KB
    const int  srow = wid * 32 + (lane >> 3);
    const int  scol = (lane & 7) * 8;
    const long gA0  = (long)(bm * 128 + srow) * H_DIM + scol;
    const long gB0  = (long)(bn * 128 + srow) * H_DIM + scol;
    const int  lds0 = wid * 2048;  // elements (wid*4096 bytes)

    // fragment read geometry (16x16x32: row=lane&15, k=(lane>>4)*8)
    const int arow = wm * 64 + (lane & 15);
    const int brow = wn * 64 + (lane & 15);
    const int koff = (lane >> 4) * 8;

    f32x4 accg[4][4] = {};
    f32x4 accu[4][4] = {};

    for (int kt = 0; kt < H_DIM / 64; ++kt) {
        __syncthreads();
        const int kb = kt * 64;
        #pragma unroll
        for (int i = 0; i < 4; ++i) {
            const long go = (long)i * (8 * H_DIM);
            const int  lo = lds0 + i * 512;
            gload16(X  + gA0 + go + kb, sA  + lo);
            gload16(W1 + gB0 + go + kb, sB1 + lo);
            gload16(W2 + gB0 + go + kb, sB2 + lo);
        }
        __syncthreads();
        #pragma unroll
        for (int kk = 0; kk < 2; ++kk) {
            bf16x8 af[4], b1f[4], b2f[4];
            const int ko = kk * 32 + koff;
            #pragma unroll
            for (int mi = 0; mi < 4; ++mi)
                af[mi] = *(const bf16x8*)(sA + (arow + mi * 16) * 64 + ko);
            #pragma unroll
            for (int ni = 0; ni < 4; ++ni) {
                b1f[ni] = *(const bf16x8*)(sB1 + (brow + ni * 16) * 64 + ko);
                b2f[ni] = *(const bf16x8*)(sB2 + (brow + ni * 16) * 64 + ko);
            }
            #pragma unroll
            for (int mi = 0; mi < 4; ++mi)
                #pragma unroll
                for (int ni = 0; ni < 4; ++ni) {
                    accg[mi][ni] = __builtin_amdgcn_mfma_f32_16x16x32_bf16(
                        af[mi], b1f[ni], accg[mi][ni], 0, 0, 0);
                    accu[mi][ni] = __builtin_amdgcn_mfma_f32_16x16x32_bf16(
                        af[mi], b2f[ni], accu[mi][ni], 0, 0, 0);
                }
        }
    }

    // epilogue: silu(gate)*up -> bf16
    const int orow0 = bm * 128 + wm * 64 + ((lane >> 4) << 2);
    const int ocol0 = bn * 128 + wn * 64 + (lane & 15);
    #pragma unroll
    for (int mi = 0; mi < 4; ++mi)
        #pragma unroll
        for (int ni = 0; ni < 4; ++ni) {
            const f32x4 g = accg[mi][ni];
            const f32x4 u = accu[mi][ni];
            #pragma unroll
            for (int r = 0; r < 4; ++r) {
                const float gv = g[r];
                const float hv = (gv / (1.0f + __expf(-gv))) * u[r];
                Hout[(long)(orow0 + mi * 16 + r) * F_DIM + (ocol0 + ni * 16)] = f2bf(hv);
            }
        }
}

// ---- GEMM2: Out = H * W3^T.  H [T,F] bf16, W3 [H,F] bf16, Out [T,H] f32 ----
__global__ __launch_bounds__(256, 2)
void gemm2_out(const unsigned short* __restrict__ A,
               const unsigned short* __restrict__ B,
               float* __restrict__ Out)
{
    __shared__ __align__(16) unsigned short sA[128 * 64];
    __shared__ __align__(16) unsigned short sB[128 * 64];

    const int tid  = threadIdx.x;
    const int lane = tid & 63;
    const int wid  = tid >> 6;
    const int wm   = wid >> 1;
    const int wn   = wid & 1;
    const int bm   = blockIdx.y;
    const int bn   = blockIdx.x;

    const int  srow = wid * 32 + (lane >> 3);
    const int  scol = (lane & 7) * 8;
    const long gA0  = (long)(bm * 128 + srow) * F_DIM + scol;
    const long gB0  = (long)(bn * 128 + srow) * F_DIM + scol;
    const int  lds0 = wid * 2048;

    const int arow = wm * 64 + (lane & 15);
    const int brow = wn * 64 + (lane & 15);
    const int koff = (lane >> 4) * 8;

    f32x4 acc[4][4] = {};

    for (int kt = 0; kt < F_DIM / 64; ++kt) {
        __syncthreads();
        const int kb = kt * 64;
        #pragma unroll
        for (int i = 0; i < 4; ++i) {
            const long go = (long)i * (8 * F_DIM);
            const int  lo = lds0 + i * 512;
            gload16(A + gA0 + go + kb, sA + lo);
            gload16(B + gB0 + go + kb, sB + lo);
        }
        __syncthreads();
        #pragma unroll
        for (int kk = 0; kk < 2; ++kk) {
            bf16x8 af[4], bf[4];
            const int ko = kk * 32 + koff;
            #pragma unroll
            for (int mi = 0; mi < 4; ++mi)
                af[mi] = *(const bf16x8*)(sA + (arow + mi * 16) * 64 + ko);
            #pragma unroll
            for (int ni = 0; ni < 4; ++ni)
                bf[ni] = *(const bf16x8*)(sB + (brow + ni * 16) * 64 + ko);
            #pragma unroll
            for (int mi = 0; mi < 4; ++mi)
                #pragma unroll
                for (int ni = 0; ni < 4; ++ni)
                    acc[mi][ni] = __builtin_amdgcn_mfma_f32_16x16x32_bf16(
                        af[mi], bf[ni], acc[mi][ni], 0, 0, 0);
        }
    }

    const int orow0 = bm * 128 + wm * 64 + ((lane >> 4) << 2);
    const int ocol0 = bn * 128 + wn * 64 + (lane & 15);
    #pragma unroll
    for (int mi = 0; mi < 4; ++mi)
        #pragma unroll
        for (int ni = 0; ni < 4; ++ni) {
            const f32x4 c = acc[mi][ni];
            #pragma unroll
            for (int r = 0; r < 4; ++r)
                Out[(long)(orow0 + mi * 16 + r) * H_DIM + (ocol0 + ni * 16)] = c[r];
        }
}

extern "C" void kernel_launch(void* const* d_in, const int* in_sizes, int n_in,
                              void* d_out, int out_size, void* d_ws, size_t ws_size,
                              hipStream_t stream)
{
    const int*   eidx = (const int*)d_in[0];
    const float* x    = (const float*)d_in[1];
    const float* w1   = (const float*)d_in[2];
    const float* w2   = (const float*)d_in[3];
    const float* w3   = (const float*)d_in[4];
    float* out = (float*)d_out;

    unsigned short* Xb  = (unsigned short*)d_ws;
    unsigned short* W1b = Xb  + (long)T_DIM * H_DIM;
    unsigned short* W2b = W1b + (long)F_DIM * H_DIM;
    unsigned short* W3b = W2b + (long)F_DIM * H_DIM;
    unsigned short* Hb  = W3b + (long)H_DIM * F_DIM;

    cvt_f32_bf16<<<2048, 256, 0, stream>>>(x,  nullptr, 0, Xb, (long)T_DIM * H_DIM);
    cvt_f32_bf16<<<2048, 256, 0, stream>>>(w1, eidx, (long)F_DIM * H_DIM, W1b, (long)F_DIM * H_DIM);
    cvt_f32_bf16<<<2048, 256, 0, stream>>>(w2, eidx, (long)F_DIM * H_DIM, W2b, (long)F_DIM * H_DIM);
    cvt_f32_bf16<<<2048, 256, 0, stream>>>(w3, eidx, (long)H_DIM * F_DIM, W3b, (long)H_DIM * F_DIM);

    gemm1_swiglu<<<dim3(F_DIM / 128, T_DIM / 128), 256, 0, stream>>>(Xb, W1b, W2b, Hb);
    gemm2_out  <<<dim3(H_DIM / 128, T_DIM / 128), 256, 0, stream>>>(Hb, W3b, out);
}

// Round 2
// 588.884 us; speedup vs baseline: 1.1216x; 1.1216x over previous
//
#include <hip/hip_runtime.h>
#include <hip/hip_bf16.h>

#define T_DIM 8192
#define H_DIM 2048
#define F_DIM 5632

typedef __attribute__((ext_vector_type(4))) float f32x4;
typedef __attribute__((ext_vector_type(8))) short bf16x8;

static __device__ __forceinline__ void gload16(const void* g, void* l) {
    __builtin_amdgcn_global_load_lds(
        (const __attribute__((address_space(1))) void*)g,
        (__attribute__((address_space(3))) void*)l,
        16, 0, 0);
}

static __device__ __forceinline__ unsigned short f2bf(float f) {
    unsigned int u = __float_as_uint(f);
    u += 0x7fffu + ((u >> 16) & 1u);
    return (unsigned short)(u >> 16);
}

// ---- f32 -> bf16 conversion (optionally expert-sliced) ----
__global__ __launch_bounds__(256)
void cvt_f32_bf16(const float* __restrict__ base, const int* __restrict__ eidx,
                  long per_expert, unsigned short* __restrict__ dst, long n)
{
    const float* src = base;
    if (eidx) src += (long)(*eidx) * per_expert;
    const long stride = (long)gridDim.x * blockDim.x;
    for (long i = (long)blockIdx.x * blockDim.x + threadIdx.x; i * 4 < n; i += stride) {
        const float4 v = *(const float4*)(src + i * 4);
        ushort4 o;
        o.x = f2bf(v.x); o.y = f2bf(v.y); o.z = f2bf(v.z); o.w = f2bf(v.w);
        *(ushort4*)(dst + i * 4) = o;
    }
}

// ---- shared helpers for the 256x256 / BK=64 8-wave pipelined GEMM ----
// Staging: half-tile (2 of 4 row-quarters) of a 256x64 bf16 tile.
// LDS dest is lane-linear (t*16B within quarter); global source column is
// inverse-XOR-swizzled so that swizzled ds_reads see the right data (rule #21).
static __device__ __forceinline__ void stage_half(const unsigned short* __restrict__ g,
                                                  long grow0, long ldk, long kb,
                                                  unsigned short* l, int t, int i0)
{
    const int r  = t >> 3;
    const int cc = ((t & 7) ^ (r & 7)) << 3;   // swizzled source column (elems)
    #pragma unroll
    for (int i = i0; i < i0 + 2; ++i)
        gload16(g + (grow0 + i * 64 + r) * ldk + kb + cc,
                l + i * 4096 + t * 8);
}

// Swizzled fragment read: logical 8-elem chunk (kk*4+q) of row -> physical
// chunk ^(row&7). 16B aligned -> ds_read_b128, conflict-free.
static __device__ __forceinline__ bf16x8 ldsfrag(const unsigned short* base,
                                                 int row, int kk, int q)
{
    return *(const bf16x8*)(base + row * 64 + (((kk * 4 + q) ^ (row & 7)) << 3));
}

#define PHASE_BODY(p, STAGE_STMT)                                              \
    {                                                                          \
        bf16x8 af[2][2];                                                       \
        _Pragma("unroll")                                                      \
        for (int l_ = 0; l_ < 2; ++l_)                                         \
            _Pragma("unroll")                                                  \
            for (int kk = 0; kk < 2; ++kk)                                     \
                af[l_][kk] = ldsfrag(la, wm * 128 + (p) * 32 + l_ * 16 + lr, kk, q); \
        STAGE_STMT;                                                            \
        __builtin_amdgcn_s_barrier();                                          \
        __builtin_amdgcn_s_setprio(1);                                         \
        _Pragma("unroll")                                                      \
        for (int l_ = 0; l_ < 2; ++l_)                                         \
            _Pragma("unroll")                                                  \
            for (int ni = 0; ni < 4; ++ni)                                     \
                _Pragma("unroll")                                              \
                for (int kk = 0; kk < 2; ++kk)                                 \
                    acc[(p) * 2 + l_][ni] = __builtin_amdgcn_mfma_f32_16x16x32_bf16( \
                        af[l_][kk], bf[ni][kk], acc[(p) * 2 + l_][ni], 0, 0, 0);     \
        __builtin_amdgcn_s_setprio(0);                                         \
        __builtin_amdgcn_s_barrier();                                          \
    }

// ---- GEMM1 fused: gate = X*W1^T, up = X*W2^T, H = silu(gate)*up -> bf16 ----
// B-tile rows 0-127 = W1[bn*128 ..], rows 128-255 = W2[bn*128 ..].
__global__ __launch_bounds__(512, 2)
void gemm1_swiglu(const unsigned short* __restrict__ X,
                  const unsigned short* __restrict__ W1,
                  const unsigned short* __restrict__ W2,
                  unsigned short* __restrict__ Hout)
{
    __shared__ __align__(16) unsigned short sAll[4 * 16384];  // 128 KiB

    const int tid  = threadIdx.x;
    const int lane = tid & 63;
    const int wid  = tid >> 6;
    const int wm   = wid >> 2;      // 0..1
    const int wn   = wid & 3;       // 0..3 (0,1 = gate / W1; 2,3 = up / W2)
    const int q    = lane >> 4;
    const int lr   = lane & 15;

    const int nwg = gridDim.x;
    const int bid = blockIdx.x;
    const int cpx = nwg >> 3;                       // nwg % 8 == 0
    const int swz = (bid & 7) * cpx + (bid >> 3);
    const int NBN = F_DIM / 128;                    // 44
    const int bm  = swz / NBN;
    const int bn  = swz % NBN;

    const long arow0 = (long)bm * 256;
    const long b1r0  = (long)bn * 128;
    const long b2r0  = (long)bn * 128 - 128;        // +i*64 (i>=2) recovers rows
    const int  NK    = H_DIM / 64;                  // 32

    f32x4 acc[8][4] = {};

    // prologue: A(0),B(0) -> buf0 ; B(1) -> buf1   (A(1) issued at TOP(0))
    stage_half(X,  arow0, H_DIM, 0, sAll,          tid, 0);
    stage_half(X,  arow0, H_DIM, 0, sAll,          tid, 2);
    stage_half(W1, b1r0,  H_DIM, 0, sAll + 16384,  tid, 0);
    stage_half(W2, b2r0,  H_DIM, 0, sAll + 16384,  tid, 2);
    stage_half(W1, b1r0,  H_DIM, 64, sAll + 49152, tid, 0);
    stage_half(W2, b2r0,  H_DIM, 64, sAll + 49152, tid, 2);

    for (int j = 0; j < NK; ++j) {
        unsigned short* la = sAll + (j & 1) * 32768;
        unsigned short* lb = la + 16384;

        if (j + 1 < NK) {   // stage A(j+1) into other buffer (its A was consumed last iter)
            unsigned short* na = sAll + ((j + 1) & 1) * 32768;
            stage_half(X, arow0, H_DIM, (long)(j + 1) * 64, na, tid, 0);
            stage_half(X, arow0, H_DIM, (long)(j + 1) * 64, na, tid, 2);
            asm volatile("s_waitcnt vmcnt(8)" ::: "memory");  // drains tile j (8 newer: B(j+1),A(j+1))
        } else {
            asm volatile("s_waitcnt vmcnt(0)" ::: "memory");
        }
        __builtin_amdgcn_s_barrier();

        // phase 0: hoist all B-frags (B region of this buffer is dead afterwards)
        bf16x8 bf[4][2];
        #pragma unroll
        for (int ni = 0; ni < 4; ++ni)
            #pragma unroll
            for (int kk = 0; kk < 2; ++kk)
                bf[ni][kk] = ldsfrag(lb, wn * 64 + ni * 16 + lr, kk, q);

        PHASE_BODY(0, {})
        PHASE_BODY(1, { if (j + 2 < NK) stage_half(W1, b1r0, H_DIM, (long)(j + 2) * 64, lb, tid, 0); })
        PHASE_BODY(2, { if (j + 2 < NK) stage_half(W2, b2r0, H_DIM, (long)(j + 2) * 64, lb, tid, 2); })
        PHASE_BODY(3, {})
    }

    // epilogue: exchange `up` via LDS (all VMEM drained; all reads done)
    float* slab = (float*)sAll;
    float* s = slab + (wm * 2 + (wn & 1)) * 8192;   // 128x64 f32 per pair
    if (wn >= 2) {
        #pragma unroll
        for (int mi = 0; mi < 8; ++mi)
            #pragma unroll
            for (int ni = 0; ni < 4; ++ni)
                #pragma unroll
                for (int r = 0; r < 4; ++r)
                    s[(mi * 16 + q * 4 + r) * 64 + ni * 16 + lr] = acc[mi][ni][r];
    }
    __syncthreads();   // real sync: drains lgkm for cross-wave LDS visibility
    if (wn < 2) {
        const long orow = (long)bm * 256 + wm * 128;
        const long ocol = (long)bn * 128 + wn * 64;
        #pragma unroll
        for (int mi = 0; mi < 8; ++mi)
            #pragma unroll
            for (int ni = 0; ni < 4; ++ni)
                #pragma unroll
                for (int r = 0; r < 4; ++r) {
                    const float g = acc[mi][ni][r];
                    const float u = s[(mi * 16 + q * 4 + r) * 64 + ni * 16 + lr];
                    const float h = (g / (1.0f + __expf(-g))) * u;
                    Hout[(orow + mi * 16 + q * 4 + r) * F_DIM + (ocol + ni * 16 + lr)] = f2bf(h);
                }
    }
}

// ---- GEMM2: Out = H * W3^T.  H [T,F] bf16, W3 [H,F] bf16, Out [T,H] f32 ----
__global__ __launch_bounds__(512, 2)
void gemm2_out(const unsigned short* __restrict__ A,
               const unsigned short* __restrict__ B,
               float* __restrict__ Out)
{
    __shared__ __align__(16) unsigned short sAll[4 * 16384];  // 128 KiB

    const int tid  = threadIdx.x;
    const int lane = tid & 63;
    const int wid  = tid >> 6;
    const int wm   = wid >> 2;
    const int wn   = wid & 3;
    const int q    = lane >> 4;
    const int lr   = lane & 15;

    const int nwg = gridDim.x;                     // 256
    const int bid = blockIdx.x;
    const int cpx = nwg >> 3;
    const int swz = (bid & 7) * cpx + (bid >> 3);
    const int NBN = H_DIM / 256;                   // 8
    const int bm  = swz / NBN;
    const int bn  = swz % NBN;

    const long arow0 = (long)bm * 256;
    const long brow0 = (long)bn * 256;
    const int  NK    = F_DIM / 64;                 // 88

    f32x4 acc[8][4] = {};

    stage_half(A, arow0, F_DIM, 0, sAll,          tid, 0);
    stage_half(A, arow0, F_DIM, 0, sAll,          tid, 2);
    stage_half(B, brow0, F_DIM, 0, sAll + 16384,  tid, 0);
    stage_half(B, brow0, F_DIM, 0, sAll + 16384,  tid, 2);
    stage_half(B, brow0, F_DIM, 64, sAll + 49152, tid, 0);
    stage_half(B, brow0, F_DIM, 64, sAll + 49152, tid, 2);

    for (int j = 0; j < NK; ++j) {
        unsigned short* la = sAll + (j & 1) * 32768;
        unsigned short* lb = la + 16384;

        if (j + 1 < NK) {
            unsigned short* na = sAll + ((j + 1) & 1) * 32768;
            stage_half(A, arow0, F_DIM, (long)(j + 1) * 64, na, tid, 0);
            stage_half(A, arow0, F_DIM, (long)(j + 1) * 64, na, tid, 2);
            asm volatile("s_waitcnt vmcnt(8)" ::: "memory");
        } else {
            asm volatile("s_waitcnt vmcnt(0)" ::: "memory");
        }
        __builtin_amdgcn_s_barrier();

        bf16x8 bf[4][2];
        #pragma unroll
        for (int ni = 0; ni < 4; ++ni)
            #pragma unroll
            for (int kk = 0; kk < 2; ++kk)
                bf[ni][kk] = ldsfrag(lb, wn * 64 + ni * 16 + lr, kk, q);

        PHASE_BODY(0, {})
        PHASE_BODY(1, { if (j + 2 < NK) stage_half(B, brow0, F_DIM, (long)(j + 2) * 64, lb, tid, 0); })
        PHASE_BODY(2, { if (j + 2 < NK) stage_half(B, brow0, F_DIM, (long)(j + 2) * 64, lb, tid, 2); })
        PHASE_BODY(3, {})
    }

    const long orow = (long)bm * 256 + wm * 128;
    const long ocol = (long)bn * 256 + wn * 64;
    #pragma unroll
    for (int mi = 0; mi < 8; ++mi)
        #pragma unroll
        for (int ni = 0; ni < 4; ++ni)
            #pragma unroll
            for (int r = 0; r < 4; ++r)
                Out[(orow + mi * 16 + q * 4 + r) * H_DIM + (ocol + ni * 16 + lr)] = acc[mi][ni][r];
}

extern "C" void kernel_launch(void* const* d_in, const int* in_sizes, int n_in,
                              void* d_out, int out_size, void* d_ws, size_t ws_size,
                              hipStream_t stream)
{
    const int*   eidx = (const int*)d_in[0];
    const float* x    = (const float*)d_in[1];
    const float* w1   = (const float*)d_in[2];
    const float* w2   = (const float*)d_in[3];
    const float* w3   = (const float*)d_in[4];
    float* out = (float*)d_out;

    unsigned short* Xb  = (unsigned short*)d_ws;
    unsigned short* W1b = Xb  + (long)T_DIM * H_DIM;
    unsigned short* W2b = W1b + (long)F_DIM * H_DIM;
    unsigned short* W3b = W2b + (long)F_DIM * H_DIM;
    unsigned short* Hb  = W3b + (long)H_DIM * F_DIM;

    cvt_f32_bf16<<<2048, 256, 0, stream>>>(x,  nullptr, 0, Xb, (long)T_DIM * H_DIM);
    cvt_f32_bf16<<<2048, 256, 0, stream>>>(w1, eidx, (long)F_DIM * H_DIM, W1b, (long)F_DIM * H_DIM);
    cvt_f32_bf16<<<2048, 256, 0, stream>>>(w2, eidx, (long)F_DIM * H_DIM, W2b, (long)F_DIM * H_DIM);
    cvt_f32_bf16<<<2048, 256, 0, stream>>>(w3, eidx, (long)H_DIM * F_DIM, W3b, (long)H_DIM * F_DIM);

    gemm1_swiglu<<<(T_DIM / 256) * (F_DIM / 128), 512, 0, stream>>>(Xb, W1b, W2b, Hb);
    gemm2_out  <<<(T_DIM / 256) * (H_DIM / 256), 512, 0, stream>>>(Hb, W3b, out);
}